// Round 1
// baseline (961.633 us; speedup 1.0000x reference)
//
#include <hip/hip_runtime.h>
#include <hip/hip_bf16.h>
#include <stdint.h>

#define NE 8
#define DM 1024
#define DH 4096
#define T_TOK 8192
#define NA 16384          // T_TOK * TOP_K assignments
#define BM 128
#define BN 128
#define BK 64
#define MAX_TILES 128     // ceil(NA / BM) worst case per expert

typedef __attribute__((ext_vector_type(8))) short short8;
typedef __attribute__((ext_vector_type(4))) float f32x4;

typedef const __attribute__((address_space(1))) void cas1void;
typedef __attribute__((address_space(3))) void as3void;
// global -> LDS async copy, 16B per lane; LDS dest is wave-uniform base + lane*16
#define GL2L(gp, lp) __builtin_amdgcn_global_load_lds((cas1void*)(uintptr_t)(gp), (as3void*)(uintptr_t)(lp), 16, 0, 0)

__device__ __forceinline__ unsigned short f2bf(float f) {
  union { float f; unsigned u; } v; v.f = f;
  unsigned r = (v.u + 0x7FFFu + ((v.u >> 16) & 1u)) >> 16;
  return (unsigned short)r;
}
__device__ __forceinline__ float geluf(float x) {
  return 0.5f * x * (1.0f + erff(x * 0.70710678118654752f));
}

// ---------------- routing ----------------
__global__ void k_hist(const int* __restrict__ idx, int* __restrict__ counts) {
  int a = blockIdx.x * 256 + threadIdx.x;
  if (a < NA) atomicAdd(&counts[idx[a]], 1);
}

__global__ void k_offsets(const int* __restrict__ counts, int* __restrict__ offs) {
  if (threadIdx.x == 0) {
    int s = 0;
    for (int e = 0; e < NE; ++e) { offs[e] = s; s += counts[e]; }
    offs[NE] = s;
  }
}

__global__ void k_scatter(const int* __restrict__ idx, const float* __restrict__ p,
                          const int* __restrict__ offs, int* __restrict__ cursor,
                          int* __restrict__ btok, float* __restrict__ gate) {
  int a = blockIdx.x * 256 + threadIdx.x;
  if (a < NA) {
    int e = idx[a];
    int pos = offs[e] + atomicAdd(&cursor[e], 1);
    btok[pos] = a >> 1;
    gate[pos] = p[a];
  }
}

// ---------------- dtype prep ----------------
__global__ void k_cvt_x(const float* __restrict__ x, unsigned short* __restrict__ xb) {
  int i = (blockIdx.x * 256 + threadIdx.x) * 8;
  float4 v0 = *(const float4*)(x + i);
  float4 v1 = *(const float4*)(x + i + 4);
  ushort4 o0, o1;
  o0.x = f2bf(v0.x); o0.y = f2bf(v0.y); o0.z = f2bf(v0.z); o0.w = f2bf(v0.w);
  o1.x = f2bf(v1.x); o1.y = f2bf(v1.y); o1.z = f2bf(v1.z); o1.w = f2bf(v1.w);
  *(ushort4*)(xb + i) = o0;
  *(ushort4*)(xb + i + 4) = o1;
}

// in: [E][R][C] f32  ->  out: [E][C][R] bf16
__global__ void k_transpose(const float* __restrict__ in, unsigned short* __restrict__ out,
                            int R, int C) {
  __shared__ float tile[64][65];
  size_t base = (size_t)blockIdx.z * R * C;
  const float* src = in + base;
  unsigned short* dst = out + base;
  int c0 = blockIdx.x * 64, r0 = blockIdx.y * 64;
  int tid = threadIdx.x;
  int tr = tid >> 4;          // 0..15
  int tc = (tid & 15) * 4;    // 0..60
#pragma unroll
  for (int rr = 0; rr < 64; rr += 16) {
    float4 v = *(const float4*)(src + (size_t)(r0 + tr + rr) * C + c0 + tc);
    tile[tr + rr][tc + 0] = v.x; tile[tr + rr][tc + 1] = v.y;
    tile[tr + rr][tc + 2] = v.z; tile[tr + rr][tc + 3] = v.w;
  }
  __syncthreads();
#pragma unroll
  for (int cc = 0; cc < 64; cc += 16) {
    int oc = tr + cc;         // local col of input -> out row
    ushort4 o;
    o.x = f2bf(tile[tc + 0][oc]); o.y = f2bf(tile[tc + 1][oc]);
    o.z = f2bf(tile[tc + 2][oc]); o.w = f2bf(tile[tc + 3][oc]);
    *(ushort4*)(dst + (size_t)(c0 + oc) * R + r0 + tc) = o;
  }
}

// ---------------- grouped GEMMs ----------------
// up: h[slot][n] = gelu( sum_k xb[tok[slot]][k] * wupT[e][n][k] ), n in [0,4096)
__global__ __launch_bounds__(256, 2) void k_up(
    const unsigned short* __restrict__ xb, const unsigned short* __restrict__ wupT,
    const int* __restrict__ offs, const int* __restrict__ btok,
    unsigned short* __restrict__ h) {
  int e = blockIdx.x >> 7;
  int tile = blockIdx.x & (MAX_TILES - 1);
  int beg = offs[e], cnt = offs[e + 1] - beg;
  int m0 = tile * BM;
  if (m0 >= cnt) return;
  int n0 = blockIdx.y * BN;
  __shared__ short sA[BM * BK];
  __shared__ short sB[BN * BK];
  __shared__ int stok[BM];
  int tid = threadIdx.x;
  if (tid < BM) stok[tid] = btok[beg + min(m0 + tid, cnt - 1)];
  __syncthreads();
  int wid = tid >> 6, lane = tid & 63;
  int wm = wid & 1, wn = wid >> 1;
  int sr = lane >> 3, sc = (lane & 7) * 8;
  const unsigned short* pa[4]; const unsigned short* pb[4];
  short* la[4]; short* lb[4];
#pragma unroll
  for (int j = 0; j < 4; ++j) {
    int r = wid * 32 + j * 8 + sr;
    pa[j] = xb + (size_t)stok[r] * DM + sc;
    pb[j] = wupT + ((size_t)e * DH + n0 + r) * DM + sc;
    la[j] = sA + (wid * 4 + j) * 512;   // 512 elems = 1KB per wave-chunk
    lb[j] = sB + (wid * 4 + j) * 512;
  }
  f32x4 acc[4][4];
#pragma unroll
  for (int i = 0; i < 4; ++i)
#pragma unroll
    for (int j = 0; j < 4; ++j) acc[i][j] = (f32x4){0.f, 0.f, 0.f, 0.f};
  int lr = lane & 15, lg = lane >> 4;
  for (int k0 = 0; k0 < DM; k0 += BK) {
    __syncthreads();
#pragma unroll
    for (int j = 0; j < 4; ++j) GL2L(pa[j] + k0, la[j]);
#pragma unroll
    for (int j = 0; j < 4; ++j) GL2L(pb[j] + k0, lb[j]);
    __syncthreads();
#pragma unroll
    for (int kk = 0; kk < BK; kk += 32) {
      short8 av[4], bv[4];
#pragma unroll
      for (int i = 0; i < 4; ++i)
        av[i] = *(const short8*)&sA[(wm * 64 + i * 16 + lr) * BK + kk + lg * 8];
#pragma unroll
      for (int j = 0; j < 4; ++j)
        bv[j] = *(const short8*)&sB[(wn * 64 + j * 16 + lr) * BK + kk + lg * 8];
#pragma unroll
      for (int i = 0; i < 4; ++i)
#pragma unroll
        for (int j = 0; j < 4; ++j)
          acc[i][j] = __builtin_amdgcn_mfma_f32_16x16x32_bf16(av[i], bv[j], acc[i][j], 0, 0, 0);
    }
  }
#pragma unroll
  for (int i = 0; i < 4; ++i) {
#pragma unroll
    for (int q = 0; q < 4; ++q) {
      int row = wm * 64 + i * 16 + lg * 4 + q;
      if (m0 + row < cnt) {
        size_t orow = (size_t)(beg + m0 + row) * DH + n0;
#pragma unroll
        for (int j = 0; j < 4; ++j) {
          int col = wn * 64 + j * 16 + lr;
          h[orow + col] = f2bf(geluf(acc[i][j][q]));
        }
      }
    }
  }
}

// down: y[tok[slot]][n] += gate[slot] * sum_k h[slot][k] * wdnT[e][n][k], n in [0,1024)
__global__ __launch_bounds__(256, 2) void k_down(
    const unsigned short* __restrict__ h, const unsigned short* __restrict__ wdnT,
    const int* __restrict__ offs, const int* __restrict__ btok,
    const float* __restrict__ gate, float* __restrict__ y) {
  int e = blockIdx.x >> 7;
  int tile = blockIdx.x & (MAX_TILES - 1);
  int beg = offs[e], cnt = offs[e + 1] - beg;
  int m0 = tile * BM;
  if (m0 >= cnt) return;
  int n0 = blockIdx.y * BN;
  __shared__ short sA[BM * BK];
  __shared__ short sB[BN * BK];
  __shared__ int stok[BM];
  __shared__ float sg[BM];
  __shared__ int sslot[BM];
  int tid = threadIdx.x;
  if (tid < BM) {
    int r = min(m0 + tid, cnt - 1);
    sslot[tid] = beg + r;
    stok[tid] = btok[beg + r];
    sg[tid] = gate[beg + r];
  }
  __syncthreads();
  int wid = tid >> 6, lane = tid & 63;
  int wm = wid & 1, wn = wid >> 1;
  int sr = lane >> 3, sc = (lane & 7) * 8;
  const unsigned short* pa[4]; const unsigned short* pb[4];
  short* la[4]; short* lb[4];
#pragma unroll
  for (int j = 0; j < 4; ++j) {
    int r = wid * 32 + j * 8 + sr;
    pa[j] = h + (size_t)sslot[r] * DH + sc;
    pb[j] = wdnT + ((size_t)e * DM + n0 + r) * DH + sc;
    la[j] = sA + (wid * 4 + j) * 512;
    lb[j] = sB + (wid * 4 + j) * 512;
  }
  f32x4 acc[4][4];
#pragma unroll
  for (int i = 0; i < 4; ++i)
#pragma unroll
    for (int j = 0; j < 4; ++j) acc[i][j] = (f32x4){0.f, 0.f, 0.f, 0.f};
  int lr = lane & 15, lg = lane >> 4;
  for (int k0 = 0; k0 < DH; k0 += BK) {
    __syncthreads();
#pragma unroll
    for (int j = 0; j < 4; ++j) GL2L(pa[j] + k0, la[j]);
#pragma unroll
    for (int j = 0; j < 4; ++j) GL2L(pb[j] + k0, lb[j]);
    __syncthreads();
#pragma unroll
    for (int kk = 0; kk < BK; kk += 32) {
      short8 av[4], bv[4];
#pragma unroll
      for (int i = 0; i < 4; ++i)
        av[i] = *(const short8*)&sA[(wm * 64 + i * 16 + lr) * BK + kk + lg * 8];
#pragma unroll
      for (int j = 0; j < 4; ++j)
        bv[j] = *(const short8*)&sB[(wn * 64 + j * 16 + lr) * BK + kk + lg * 8];
#pragma unroll
      for (int i = 0; i < 4; ++i)
#pragma unroll
        for (int j = 0; j < 4; ++j)
          acc[i][j] = __builtin_amdgcn_mfma_f32_16x16x32_bf16(av[i], bv[j], acc[i][j], 0, 0, 0);
    }
  }
#pragma unroll
  for (int i = 0; i < 4; ++i) {
#pragma unroll
    for (int q = 0; q < 4; ++q) {
      int row = wm * 64 + i * 16 + lg * 4 + q;
      if (m0 + row < cnt) {
        float g = sg[row];
        int t = stok[row];
#pragma unroll
        for (int j = 0; j < 4; ++j) {
          int col = n0 + wn * 64 + j * 16 + lr;
          atomicAdd(&y[(size_t)t * DM + col], acc[i][j][q] * g);
        }
      }
    }
  }
}

extern "C" void kernel_launch(void* const* d_in, const int* in_sizes, int n_in,
                              void* d_out, int out_size, void* d_ws, size_t ws_size,
                              hipStream_t stream) {
  (void)in_sizes; (void)n_in; (void)ws_size;
  const float* x   = (const float*)d_in[0];
  const float* p   = (const float*)d_in[1];
  const int*   idx = (const int*)d_in[2];
  const float* wup = (const float*)d_in[3];
  const float* wdn = (const float*)d_in[4];
  float* y = (float*)d_out;
  char* ws = (char*)d_ws;
  // ws layout (bytes)
  int* counts = (int*)(ws + 0);
  int* cursor = (int*)(ws + 64);
  int* offs   = (int*)(ws + 128);                 // 9 ints
  int* btok   = (int*)(ws + 256);                 // 16384 ints
  float* gate = (float*)(ws + 256 + 65536);       // 16384 f32
  unsigned short* xb   = (unsigned short*)(ws + 131328);               // 8192*1024 bf16
  unsigned short* wupT = (unsigned short*)(ws + 131328 + 16777216);    // [8][4096][1024] bf16
  unsigned short* wdnT = wupT + (size_t)NE * DH * DM;                  // [8][1024][4096] bf16
  unsigned short* h    = wdnT + (size_t)NE * DM * DH;                  // [16384][4096] bf16

  hipMemsetAsync(ws, 0, 256, stream);
  hipMemsetAsync(d_out, 0, (size_t)out_size * sizeof(float), stream);
  k_hist<<<NA / 256, 256, 0, stream>>>(idx, counts);
  k_offsets<<<1, 64, 0, stream>>>(counts, offs);
  k_scatter<<<NA / 256, 256, 0, stream>>>(idx, p, offs, cursor, btok, gate);
  k_cvt_x<<<(T_TOK * DM) / (256 * 8), 256, 0, stream>>>(x, xb);
  k_transpose<<<dim3(DH / 64, DM / 64, NE), 256, 0, stream>>>(wup, wupT, DM, DH);
  k_transpose<<<dim3(DM / 64, DH / 64, NE), 256, 0, stream>>>(wdn, wdnT, DH, DM);
  k_up<<<dim3(NE * MAX_TILES, DH / BN), 256, 0, stream>>>(xb, wupT, offs, btok, h);
  k_down<<<dim3(NE * MAX_TILES, DM / BN), 256, 0, stream>>>(h, wdnT, offs, btok, gate, y);
}